// Round 9
// baseline (424.197 us; speedup 1.0000x reference)
//
#include <hip/hip_runtime.h>

// HGNN conv: out = degv ⊙ (H @ ((w*deg_e) ⊙ (H^T @ (degv ⊙ (x@W))))) + bias ; w = sigmoid(H^T (x V))
// N=8192, E=4096, F=512. R9: streaming cvt_colsum (prep_h's LDS/barrier structure was
// latency-bound at 2.5 TB/s); degv fused into transHb; G2 emits (f,e) directly so the
// reduce is transpose-free. GEMMs keep R8's swizzled full-DMA staging.

#define N_NODES 8192
#define N_EDGES 4096
#define FT 512

typedef short bf16x8 __attribute__((ext_vector_type(8)));
typedef float f32x4 __attribute__((ext_vector_type(4)));
typedef unsigned short u16;
typedef unsigned int u32;

__device__ __forceinline__ u16 f2b(float f) {
    union { float f; u32 u; } v; v.f = f;
    u32 r = v.u + 0x7FFFu + ((v.u >> 16) & 1u);   // RNE
    return (u16)(r >> 16);
}
__device__ __forceinline__ float b2f(u16 h) {
    union { u32 u; float f; } v; v.u = ((u32)h) << 16; return v.f;
}

// ---------------- scalar-path kernels ----------------

__global__ __launch_bounds__(256) void zero_kernel(float* p, int n) {
    int i = blockIdx.x * 256 + threadIdx.x;
    if (i < n) p[i] = 0.f;
}

// xv[n] = x[n,:] . V ; xb = bf16(x)
__global__ __launch_bounds__(256) void xv_xb_kernel(const float* __restrict__ x,
                                                    const float* __restrict__ V,
                                                    float* __restrict__ xv,
                                                    u16* __restrict__ xb) {
    int row = blockIdx.x * 4 + (threadIdx.x >> 6);
    int lane = threadIdx.x & 63;
    const float* xr = x + (size_t)row * FT + lane * 8;
    const float* vr = V + lane * 8;
    float4 a0 = *(const float4*)xr, a1 = *(const float4*)(xr + 4);
    float4 b0 = *(const float4*)vr, b1 = *(const float4*)(vr + 4);
    float acc = a0.x * b0.x + a0.y * b0.y + a0.z * b0.z + a0.w * b0.w +
                a1.x * b1.x + a1.y * b1.y + a1.z * b1.z + a1.w * b1.w;
    u16 tmp[8] = {f2b(a0.x), f2b(a0.y), f2b(a0.z), f2b(a0.w),
                  f2b(a1.x), f2b(a1.y), f2b(a1.z), f2b(a1.w)};
    *(uint4*)(xb + (size_t)row * FT + lane * 8) = *(uint4*)tmp;
#pragma unroll
    for (int off = 32; off; off >>= 1) acc += __shfl_down(acc, off);
    if (lane == 0) xv[row] = acc;
}

// Streaming: Hbf = bf16(H) (packed pairs); zsum[e] += sum_n H[n,e]*xv[n]; desum[e] += colsum.
// Thread owns 4 e-columns over a 32-row stripe; register accumulation, 8 atomics at end.
__global__ __launch_bounds__(256) void cvt_colsum_kernel(const float* __restrict__ H,
                                                         const float* __restrict__ xv,
                                                         u16* __restrict__ Hbf,
                                                         float* __restrict__ zsum,
                                                         float* __restrict__ desum) {
    int e0 = (blockIdx.x * 256 + threadIdx.x) * 4;
    int n0 = blockIdx.y * 32;
    float z0 = 0.f, z1 = 0.f, z2 = 0.f, z3 = 0.f;
    float d0 = 0.f, d1 = 0.f, d2 = 0.f, d3 = 0.f;
#pragma unroll 4
    for (int i = 0; i < 32; i++) {
        int n = n0 + i;
        float4 h = *(const float4*)(H + (size_t)n * N_EDGES + e0);
        float xvn = xv[n];
        z0 += h.x * xvn; z1 += h.y * xvn; z2 += h.z * xvn; z3 += h.w * xvn;
        d0 += h.x; d1 += h.y; d2 += h.z; d3 += h.w;
        uint2 p;
        p.x = (h.x != 0.f ? 0x3F80u : 0u) | (h.y != 0.f ? 0x3F800000u : 0u);
        p.y = (h.z != 0.f ? 0x3F80u : 0u) | (h.w != 0.f ? 0x3F800000u : 0u);
        *(uint2*)(Hbf + (size_t)n * N_EDGES + e0) = p;
    }
    atomicAdd(zsum + e0 + 0, z0); atomicAdd(zsum + e0 + 1, z1);
    atomicAdd(zsum + e0 + 2, z2); atomicAdd(zsum + e0 + 3, z3);
    atomicAdd(desum + e0 + 0, d0); atomicAdd(desum + e0 + 1, d1);
    atomicAdd(desum + e0 + 2, d2); atomicAdd(desum + e0 + 3, d3);
}

__global__ __launch_bounds__(256) void sigmoid_kernel(const float* __restrict__ zsum,
                                                      const float* __restrict__ desum,
                                                      float* __restrict__ w_out,
                                                      float* __restrict__ wde) {
    int e = blockIdx.x * 256 + threadIdx.x;
    float z = zsum[e];
    float wv = 1.f / (1.f + expf(-z));
    w_out[e] = wv;
    wde[e] = wv * desum[e];
}

// Hbf (N,E) -> HTbf (E,N), 64x64 tiles; fused degv[n] += sum_e w[e]*H[n,e] (load phase).
__global__ __launch_bounds__(256) void transHb_kernel(const u16* __restrict__ Hbf,
                                                      const float* __restrict__ w,
                                                      u16* __restrict__ HTbf,
                                                      float* __restrict__ degv) {
    __shared__ u32 Wt[64][33];                    // Wt[n][ew] = packed e-pair (2ew, 2ew+1)
    const int t = threadIdx.x;
    const int e0 = blockIdx.x * 64, n0 = blockIdx.y * 64;
    {   // load: thread (n = t>>2, seg = t&3) handles 16 e's; accumulate degv partial
        int n = t >> 2, seg = t & 3;
        const u32* src = (const u32*)(Hbf + (size_t)(n0 + n) * N_EDGES + e0 + seg * 16);
        const float* wseg = w + e0 + seg * 16;
        float d = 0.f;
#pragma unroll
        for (int j = 0; j < 8; j++) {
            u32 v = src[j];
            Wt[n][seg * 8 + j] = v;
            if (v & 0xFFFFu) d += wseg[2 * j];
            if (v >> 16)     d += wseg[2 * j + 1];
        }
        // lanes t..t+3 share n (seg varies): pairwise shfl then one atomic
        d += __shfl_down(d, 2); d += __shfl_down(d, 1);
        if (seg == 0) atomicAdd(degv + n0 + n, d);
    }
    __syncthreads();
    {   // transpose-store: thread (e = t>>2, g = t&3) handles 16 n's
        int e = t >> 2, g = t & 3;
        int ew = e >> 1;
        u32 sel = (e & 1) ? 0x07060302u : 0x05040100u;
        u32 oo[8];
#pragma unroll
        for (int j = 0; j < 8; j++) {
            int np = g * 8 + j;
            oo[j] = __builtin_amdgcn_perm(Wt[2 * np + 1][ew], Wt[2 * np][ew], sel);
        }
        u32* drow = (u32*)(HTbf + (size_t)(e0 + e) * N_NODES + n0);
        *(uint4*)(drow + g * 8)     = *(uint4*)&oo[0];
        *(uint4*)(drow + g * 8 + 4) = *(uint4*)&oo[4];
    }
}

// W (FT,FT) fp32 -> WT (FT,FT) bf16 transposed
__global__ void wt_kernel(const float* __restrict__ src, u16* __restrict__ dst) {
    __shared__ float tile[32][33];
    int tx = threadIdx.x, ty = threadIdx.y;
    int c = blockIdx.x * 32 + tx;
    int r0 = blockIdx.y * 32;
#pragma unroll
    for (int i = 0; i < 4; i++)
        tile[ty + i * 8][tx] = src[(size_t)(r0 + ty + i * 8) * FT + c];
    __syncthreads();
#pragma unroll
    for (int i = 0; i < 4; i++)
        dst[(size_t)(blockIdx.x * 32 + ty + i * 8) * FT + r0 + tx] = f2b(tile[tx][ty + i * 8]);
}

// t2T[f,e] = f2b(wde[e] * sum_{s<8} P[s][f][e])   — pure streaming reduce, no transpose
__global__ __launch_bounds__(256) void t2red_kernel(const u16* __restrict__ P,
                                                    const float* __restrict__ wde,
                                                    u16* __restrict__ t2T) {
    int i8 = blockIdx.x * 256 + threadIdx.x;
    int base = i8 * 8;                    // over 512*4096 elems, f-major
    int e = base & (N_EDGES - 1);
    float s[8] = {0.f, 0.f, 0.f, 0.f, 0.f, 0.f, 0.f, 0.f};
#pragma unroll
    for (int sl = 0; sl < 8; sl++) {
        uint4 v = *(const uint4*)(P + (size_t)sl * FT * N_EDGES + base);
        u32 ws[4] = {v.x, v.y, v.z, v.w};
#pragma unroll
        for (int j = 0; j < 4; j++) {
            s[2 * j]     += b2f((u16)(ws[j] & 0xFFFFu));
            s[2 * j + 1] += b2f((u16)(ws[j] >> 16));
        }
    }
    float4 wa = *(const float4*)(wde + e), wb = *(const float4*)(wde + e + 4);
    u16 o[8] = {f2b(s[0] * wa.x), f2b(s[1] * wa.y), f2b(s[2] * wa.z), f2b(s[3] * wa.w),
                f2b(s[4] * wb.x), f2b(s[5] * wb.y), f2b(s[6] * wb.z), f2b(s[7] * wb.w)};
    *(uint4*)(t2T + base) = *(uint4*)o;
}

// out[n,f] = degv[n]*sum_{s<4} P[s][n][f] + bias[f]
__global__ __launch_bounds__(256) void final_kernel(const u16* __restrict__ P,
                                                    const float* __restrict__ degv,
                                                    const float* __restrict__ bias,
                                                    float* __restrict__ out) {
    int i8 = blockIdx.x * 256 + threadIdx.x;
    int base = i8 * 8;
    int n = base >> 9, f = base & 511;
    float s[8] = {0.f, 0.f, 0.f, 0.f, 0.f, 0.f, 0.f, 0.f};
#pragma unroll
    for (int sl = 0; sl < 4; sl++) {
        uint4 v = *(const uint4*)(P + (size_t)sl * N_NODES * 512 + base);
        u32 ws[4] = {v.x, v.y, v.z, v.w};
#pragma unroll
        for (int j = 0; j < 4; j++) {
            s[2 * j]     += b2f((u16)(ws[j] & 0xFFFFu));
            s[2 * j + 1] += b2f((u16)(ws[j] >> 16));
        }
    }
    float dv = degv[n];
    float4 o0, o1;
    o0.x = dv * s[0] + bias[f + 0]; o0.y = dv * s[1] + bias[f + 1];
    o0.z = dv * s[2] + bias[f + 2]; o0.w = dv * s[3] + bias[f + 3];
    o1.x = dv * s[4] + bias[f + 4]; o1.y = dv * s[5] + bias[f + 5];
    o1.z = dv * s[6] + bias[f + 6]; o1.w = dv * s[7] + bias[f + 7];
    *(float4*)(out + base) = o0;
    *(float4*)(out + base + 4) = o1;
}

// ---------------- MFMA GEMM: full-DMA staging + bank-conflict swizzle (R8) ----------------
// Tile (MT*32) x (NT*32), 4 waves (2x2). Both operands bf16 row-major, k-contiguous.
// Staging: LDS slot c <- global (row=c>>2, k-chunk q=((c&3)-(c>>3))&3); frag reads
// slot s=(quad+(row>>1))&3 -> 2-way bank alias = free.
// EPI 0: bf16 partial store at Cp + z*Ssz, row-major ldc
// EPI 1: bf16 store C[m*ldc+n] scaled by degv[n]

#define TBK 32

template <int MT, int NT, int EPI>
__global__ __launch_bounds__(256, 3)
void gemm8(const u16* __restrict__ Ap, const u16* __restrict__ Bp,
           void* __restrict__ Cp, const float* __restrict__ degv,
           int KC, int lda, int ldb, int ldc, int Ssz) {
    __shared__ __align__(16) u16 Alds[MT * 32 * TBK];
    __shared__ __align__(16) u16 Blds[NT * 32 * TBK];
    const int t = threadIdx.x;
    const int m0 = blockIdx.x * (MT * 32), n0 = blockIdx.y * (NT * 32);
    const int kbase = blockIdx.z * KC;
    const int wave = t >> 6, lane = t & 63, quad = lane >> 4, lo = lane & 15;
    const int wm = (wave >> 1) * (MT * 16), wn = (wave & 1) * (NT * 16);

    f32x4 acc[MT][NT];
#pragma unroll
    for (int a = 0; a < MT; a++)
#pragma unroll
        for (int b = 0; b < NT; b++) acc[a][b] = (f32x4){0.f, 0.f, 0.f, 0.f};

    for (int kk = 0; kk < KC; kk += TBK) {
        const int k0 = kbase + kk;
        __syncthreads();
#pragma unroll
        for (int i = 0; i < MT / 2; i++) {        // A staging, swizzled gather
            int c = t + i * 256;
            int q = ((c & 3) - (c >> 3)) & 3;
            const u16* g = Ap + (size_t)(m0 + (c >> 2)) * lda + k0 + q * 8;
            __builtin_amdgcn_global_load_lds((const u32*)g, (u32*)(Alds + c * 8), 16, 0, 0);
        }
#pragma unroll
        for (int i = 0; i < NT / 2; i++) {        // B staging, swizzled gather
            int c = t + i * 256;
            int q = ((c & 3) - (c >> 3)) & 3;
            const u16* g = Bp + (size_t)(n0 + (c >> 2)) * ldb + k0 + q * 8;
            __builtin_amdgcn_global_load_lds((const u32*)g, (u32*)(Blds + c * 8), 16, 0, 0);
        }
        __syncthreads();

        bf16x8 af[MT], bfr[NT];
#pragma unroll
        for (int mt = 0; mt < MT; mt++) {
            int m = wm + mt * 16 + lo;
            int s = (quad + (m >> 1)) & 3;
            af[mt] = *(const bf16x8*)&Alds[m * TBK + s * 8];
        }
#pragma unroll
        for (int nt = 0; nt < NT; nt++) {
            int n = wn + nt * 16 + lo;
            int s = (quad + (n >> 1)) & 3;
            bfr[nt] = *(const bf16x8*)&Blds[n * TBK + s * 8];
        }
#pragma unroll
        for (int mt = 0; mt < MT; mt++)
#pragma unroll
            for (int nt = 0; nt < NT; nt++)
                acc[mt][nt] = __builtin_amdgcn_mfma_f32_16x16x32_bf16(af[mt], bfr[nt], acc[mt][nt], 0, 0, 0);
    }

    // epilogue: D[row=quad*4+i][col=lo] per 16x16 tile
    if (EPI == 0) {
        u16* C = (u16*)Cp + (size_t)blockIdx.z * Ssz;
#pragma unroll
        for (int mt = 0; mt < MT; mt++) {
            int rb = m0 + wm + mt * 16 + quad * 4;
#pragma unroll
            for (int i = 0; i < 4; i++)
#pragma unroll
                for (int nt = 0; nt < NT; nt++)
                    C[(size_t)(rb + i) * ldc + n0 + wn + nt * 16 + lo] = f2b(acc[mt][nt][i]);
        }
    } else {
        u16* C = (u16*)Cp;
        float dv[NT];
#pragma unroll
        for (int nt = 0; nt < NT; nt++) dv[nt] = degv[n0 + wn + nt * 16 + lo];
#pragma unroll
        for (int mt = 0; mt < MT; mt++) {
            int rb = m0 + wm + mt * 16 + quad * 4;
#pragma unroll
            for (int i = 0; i < 4; i++)
#pragma unroll
                for (int nt = 0; nt < NT; nt++)
                    C[(size_t)(rb + i) * ldc + n0 + wn + nt * 16 + lo] =
                        f2b(acc[mt][nt][i] * dv[nt]);
        }
    }
}

// ---------------- launch ----------------

extern "C" void kernel_launch(void* const* d_in, const int* in_sizes, int n_in,
                              void* d_out, int out_size, void* d_ws, size_t ws_size,
                              hipStream_t stream) {
    const float* x    = (const float*)d_in[0];
    const float* H    = (const float*)d_in[1];
    const float* W    = (const float*)d_in[2];
    const float* V    = (const float*)d_in[3];
    const float* bias = (const float*)d_in[4];
    float* out  = (float*)d_out;                       // (N, FT)
    float* wout = out + (size_t)N_NODES * FT;          // (E,)
    (void)in_sizes; (void)n_in; (void)out_size; (void)ws_size;

    char* wsb = (char*)d_ws;
    float* wsf   = (float*)d_ws;
    float* xv    = wsf;               // 8192 f
    float* zsum  = wsf + 8192;        // 4096 f  ┐
    float* desum = wsf + 12288;       // 4096 f  │ zeroed together (16384 f)
    float* degv  = wsf + 16384;       // 8192 f  ┘
    float* wde   = wsf + 24576;       // 4096 f -> 114,688 B
    u16*   Hbf   = (u16*)(wsb + 114688);                 // 64 MB  -> 67,223,552
    u16*   HTbf  = (u16*)(wsb + 67223552);               // 64 MB  -> 134,332,416
    u16*   WT    = (u16*)(wsb + 134332416);              // 0.5 MB -> 134,856,704
    u16*   doutT = (u16*)(wsb + 134856704);              // 8 MB   -> 143,245,312
    u16*   t2T   = (u16*)(wsb + 143245312);              // 4 MB   -> 147,439,616
    u16*   xb    = (u16*)(wsb + 147439616);              // 8 MB   -> 155,828,224
    u16*   P     = (u16*)(wsb + 155828224);              // 32 MB  -> 189,382,656

    // scalar path
    zero_kernel<<<64, 256, 0, stream>>>(zsum, 16384);    // zsum + desum + degv
    xv_xb_kernel<<<N_NODES / 4, 256, 0, stream>>>(x, V, xv, xb);
    cvt_colsum_kernel<<<dim3(4, 256), 256, 0, stream>>>(H, xv, Hbf, zsum, desum);
    sigmoid_kernel<<<N_EDGES / 256, 256, 0, stream>>>(zsum, desum, wout, wde);
    transHb_kernel<<<dim3(N_EDGES / 64, N_NODES / 64), 256, 0, stream>>>(Hbf, wout, HTbf, degv);
    wt_kernel<<<dim3(16, 16), dim3(32, 8), 0, stream>>>(W, WT);

    // G1: doutT[f,n] = degv[n] * sum_fi WT[f,fi]*xb[n,fi]  (M=512, N=8192, K=512) 64x128 tile
    gemm8<2, 4, 1><<<dim3(FT / 64, N_NODES / 128, 1), 256, 0, stream>>>(
        WT, xb, doutT, degv, FT, FT, FT, N_NODES, 0);

    // G2: P[z][f][e] = partial sum_n doutT[f,n]*HTbf[e,n]  (M=512, N=4096, K=8192, S=8)
    gemm8<4, 4, 0><<<dim3(FT / 128, N_EDGES / 128, 8), 256, 0, stream>>>(
        doutT, HTbf, P, nullptr, N_NODES / 8, N_NODES, N_NODES, N_EDGES, FT * N_EDGES);

    // t2T[f,e] = wde[e] * sum_s P   (streaming, no transpose)
    t2red_kernel<<<(FT * N_EDGES / 8) / 256, 256, 0, stream>>>(P, wde, t2T);

    // G3: P[z][n][f] = partial sum_e Hbf[n,e]*t2T[f,e]   (M=8192, N=512, K=4096, S=4)
    gemm8<4, 4, 0><<<dim3(N_NODES / 128, FT / 128, 4), 256, 0, stream>>>(
        Hbf, t2T, P, nullptr, N_EDGES / 4, N_EDGES, N_EDGES, FT, N_NODES * FT);

    // out = degv ⊙ (sum_s P) + bias
    final_kernel<<<(N_NODES * FT / 8) / 256, 256, 0, stream>>>(P, degv, bias, out);
}

// Round 10
// 391.943 us; speedup vs baseline: 1.0823x; 1.0823x over previous
//
#include <hip/hip_runtime.h>

// HGNN conv: out = degv ⊙ (H @ ((w*deg_e) ⊙ (H^T @ (degv ⊙ (x@W))))) + bias ; w = sigmoid(H^T (x V))
// N=8192, E=4096, F=512. R10 = R8's validated structure (swizzled full-DMA gemms, G2->(e,f),
// t2t LDS reduce) with prep_h replaced by clean streaming passes:
// cvt_colsum (stream) + transHb (pure transpose) + degv (standalone branchless).

#define N_NODES 8192
#define N_EDGES 4096
#define FT 512

typedef short bf16x8 __attribute__((ext_vector_type(8)));
typedef float f32x4 __attribute__((ext_vector_type(4)));
typedef unsigned short u16;
typedef unsigned int u32;

__device__ __forceinline__ u16 f2b(float f) {
    union { float f; u32 u; } v; v.f = f;
    u32 r = v.u + 0x7FFFu + ((v.u >> 16) & 1u);   // RNE
    return (u16)(r >> 16);
}
__device__ __forceinline__ float b2f(u16 h) {
    union { u32 u; float f; } v; v.u = ((u32)h) << 16; return v.f;
}

// ---------------- scalar-path kernels ----------------

__global__ __launch_bounds__(256) void zero_kernel(float* p, int n) {
    int i = blockIdx.x * 256 + threadIdx.x;
    if (i < n) p[i] = 0.f;
}

// xv[n] = x[n,:] . V ; xb = bf16(x)
__global__ __launch_bounds__(256) void xv_xb_kernel(const float* __restrict__ x,
                                                    const float* __restrict__ V,
                                                    float* __restrict__ xv,
                                                    u16* __restrict__ xb) {
    int row = blockIdx.x * 4 + (threadIdx.x >> 6);
    int lane = threadIdx.x & 63;
    const float* xr = x + (size_t)row * FT + lane * 8;
    const float* vr = V + lane * 8;
    float4 a0 = *(const float4*)xr, a1 = *(const float4*)(xr + 4);
    float4 b0 = *(const float4*)vr, b1 = *(const float4*)(vr + 4);
    float acc = a0.x * b0.x + a0.y * b0.y + a0.z * b0.z + a0.w * b0.w +
                a1.x * b1.x + a1.y * b1.y + a1.z * b1.z + a1.w * b1.w;
    u16 tmp[8] = {f2b(a0.x), f2b(a0.y), f2b(a0.z), f2b(a0.w),
                  f2b(a1.x), f2b(a1.y), f2b(a1.z), f2b(a1.w)};
    *(uint4*)(xb + (size_t)row * FT + lane * 8) = *(uint4*)tmp;
#pragma unroll
    for (int off = 32; off; off >>= 1) acc += __shfl_down(acc, off);
    if (lane == 0) xv[row] = acc;
}

// Streaming: Hbf = bf16(H) (packed pairs); zsum[e] += sum_n H[n,e]*xv[n]; desum[e] += colsum.
__global__ __launch_bounds__(256) void cvt_colsum_kernel(const float* __restrict__ H,
                                                         const float* __restrict__ xv,
                                                         u16* __restrict__ Hbf,
                                                         float* __restrict__ zsum,
                                                         float* __restrict__ desum) {
    int e0 = (blockIdx.x * 256 + threadIdx.x) * 4;
    int n0 = blockIdx.y * 32;
    float z0 = 0.f, z1 = 0.f, z2 = 0.f, z3 = 0.f;
    float d0 = 0.f, d1 = 0.f, d2 = 0.f, d3 = 0.f;
#pragma unroll 4
    for (int i = 0; i < 32; i++) {
        int n = n0 + i;
        float4 h = *(const float4*)(H + (size_t)n * N_EDGES + e0);
        float xvn = xv[n];
        z0 += h.x * xvn; z1 += h.y * xvn; z2 += h.z * xvn; z3 += h.w * xvn;
        d0 += h.x; d1 += h.y; d2 += h.z; d3 += h.w;
        uint2 p;
        p.x = (h.x != 0.f ? 0x3F80u : 0u) | (h.y != 0.f ? 0x3F800000u : 0u);
        p.y = (h.z != 0.f ? 0x3F80u : 0u) | (h.w != 0.f ? 0x3F800000u : 0u);
        *(uint2*)(Hbf + (size_t)n * N_EDGES + e0) = p;
    }
    atomicAdd(zsum + e0 + 0, z0); atomicAdd(zsum + e0 + 1, z1);
    atomicAdd(zsum + e0 + 2, z2); atomicAdd(zsum + e0 + 3, z3);
    atomicAdd(desum + e0 + 0, d0); atomicAdd(desum + e0 + 1, d1);
    atomicAdd(desum + e0 + 2, d2); atomicAdd(desum + e0 + 3, d3);
}

__global__ __launch_bounds__(256) void sigmoid_kernel(const float* __restrict__ zsum,
                                                      const float* __restrict__ desum,
                                                      float* __restrict__ w_out,
                                                      float* __restrict__ wde) {
    int e = blockIdx.x * 256 + threadIdx.x;
    float z = zsum[e];
    float wv = 1.f / (1.f + expf(-z));
    w_out[e] = wv;
    wde[e] = wv * desum[e];
}

// Hbf (N,E) u16 -> HTbf (E,N) u16 : 64x64 tiles, pure transpose (no fused gathers)
__global__ __launch_bounds__(256) void transHb_kernel(const u16* __restrict__ Hbf,
                                                      u16* __restrict__ HTbf) {
    __shared__ u32 Wt[64][33];                    // Wt[n][ew] = packed e-pair (2ew, 2ew+1)
    const int t = threadIdx.x;
    const int e0 = blockIdx.x * 64, n0 = blockIdx.y * 64;
    {   // load: row n = t>>2, seg = t&3 loads 16 u16
        int n = t >> 2, seg = t & 3;
        const u32* src = (const u32*)(Hbf + (size_t)(n0 + n) * N_EDGES + e0 + seg * 16);
#pragma unroll
        for (int j = 0; j < 8; j++) Wt[n][seg * 8 + j] = src[j];
    }
    __syncthreads();
    {   // store: e = t>>2, g = t&3 -> 16 n's via v_perm
        int e = t >> 2, g = t & 3;
        int ew = e >> 1;
        u32 sel = (e & 1) ? 0x07060302u : 0x05040100u;
        u32 oo[8];
#pragma unroll
        for (int j = 0; j < 8; j++) {
            int np = g * 8 + j;
            oo[j] = __builtin_amdgcn_perm(Wt[2 * np + 1][ew], Wt[2 * np][ew], sel);
        }
        u32* drow = (u32*)(HTbf + (size_t)(e0 + e) * N_NODES + n0);
        *(uint4*)(drow + g * 8)     = *(uint4*)&oo[0];
        *(uint4*)(drow + g * 8 + 4) = *(uint4*)&oo[4];
    }
}

// degv[n] = Hbf[n,:] . w   (one wave per row; coalesced w loads, cndmask adds)
__global__ __launch_bounds__(256) void degv_kernel(const u16* __restrict__ Hbf,
                                                   const float* __restrict__ w,
                                                   float* __restrict__ degv) {
    int row = blockIdx.x * 4 + (threadIdx.x >> 6);
    int lane = threadIdx.x & 63;
    const uint4* hr = (const uint4*)(Hbf + (size_t)row * N_EDGES);
    float acc = 0.f;
#pragma unroll
    for (int i = 0; i < 8; i++) {
        int idx = i * 64 + lane;
        uint4 h = hr[idx];
        const float* w8 = w + idx * 8;
        float4 wa = *(const float4*)w8, wb = *(const float4*)(w8 + 4);
        acc += (h.x & 0xFFFFu) ? wa.x : 0.f;  acc += (h.x >> 16) ? wa.y : 0.f;
        acc += (h.y & 0xFFFFu) ? wa.z : 0.f;  acc += (h.y >> 16) ? wa.w : 0.f;
        acc += (h.z & 0xFFFFu) ? wb.x : 0.f;  acc += (h.z >> 16) ? wb.y : 0.f;
        acc += (h.w & 0xFFFFu) ? wb.z : 0.f;  acc += (h.w >> 16) ? wb.w : 0.f;
    }
#pragma unroll
    for (int off = 32; off; off >>= 1) acc += __shfl_down(acc, off);
    if (lane == 0) degv[row] = acc;
}

// W (FT,FT) fp32 -> WT (FT,FT) bf16 transposed
__global__ void wt_kernel(const float* __restrict__ src, u16* __restrict__ dst) {
    __shared__ float tile[32][33];
    int tx = threadIdx.x, ty = threadIdx.y;
    int c = blockIdx.x * 32 + tx;
    int r0 = blockIdx.y * 32;
#pragma unroll
    for (int i = 0; i < 4; i++)
        tile[ty + i * 8][tx] = src[(size_t)(r0 + ty + i * 8) * FT + c];
    __syncthreads();
#pragma unroll
    for (int i = 0; i < 4; i++)
        dst[(size_t)(blockIdx.x * 32 + ty + i * 8) * FT + r0 + tx] = f2b(tile[tx][ty + i * 8]);
}

// t2T[f,e] = f2b(wde[e] * sum_{s<8} P[s][e][f])
__global__ void t2t_kernel(const u16* __restrict__ P, const float* __restrict__ wde,
                           u16* __restrict__ t2T) {
    __shared__ float tile[32][33];
    int tx = threadIdx.x, ty = threadIdx.y;
    int f0 = blockIdx.x * 32, e0 = blockIdx.y * 32;
#pragma unroll
    for (int i = 0; i < 4; i++) {
        int e = e0 + ty + i * 8;
        size_t idx = (size_t)e * 512 + f0 + tx;
        float s = 0.f;
#pragma unroll
        for (int sl = 0; sl < 8; sl++)
            s += b2f(P[idx + (size_t)sl * N_EDGES * 512]);
        tile[ty + i * 8][tx] = wde[e] * s;
    }
    __syncthreads();
#pragma unroll
    for (int i = 0; i < 4; i++)
        t2T[(size_t)(f0 + ty + i * 8) * N_EDGES + e0 + tx] = f2b(tile[tx][ty + i * 8]);
}

// out[n,f] = degv[n]*sum_{s<4} P[s][n][f] + bias[f]
__global__ __launch_bounds__(256) void final_kernel(const u16* __restrict__ P,
                                                    const float* __restrict__ degv,
                                                    const float* __restrict__ bias,
                                                    float* __restrict__ out) {
    int i8 = blockIdx.x * 256 + threadIdx.x;
    int base = i8 * 8;
    int n = base >> 9, f = base & 511;
    float s[8] = {0.f, 0.f, 0.f, 0.f, 0.f, 0.f, 0.f, 0.f};
#pragma unroll
    for (int sl = 0; sl < 4; sl++) {
        uint4 v = *(const uint4*)(P + (size_t)sl * N_NODES * 512 + base);
        u32 ws[4] = {v.x, v.y, v.z, v.w};
#pragma unroll
        for (int j = 0; j < 4; j++) {
            s[2 * j]     += b2f((u16)(ws[j] & 0xFFFFu));
            s[2 * j + 1] += b2f((u16)(ws[j] >> 16));
        }
    }
    float dv = degv[n];
    float4 o0, o1;
    o0.x = dv * s[0] + bias[f + 0]; o0.y = dv * s[1] + bias[f + 1];
    o0.z = dv * s[2] + bias[f + 2]; o0.w = dv * s[3] + bias[f + 3];
    o1.x = dv * s[4] + bias[f + 4]; o1.y = dv * s[5] + bias[f + 5];
    o1.z = dv * s[6] + bias[f + 6]; o1.w = dv * s[7] + bias[f + 7];
    *(float4*)(out + base) = o0;
    *(float4*)(out + base + 4) = o1;
}

// ---------------- MFMA GEMM: full-DMA staging + bank-conflict swizzle (R8) ----------------
// Tile (MT*32) x (NT*32), 4 waves (2x2). Both operands bf16 row-major, k-contiguous.
// Staging: LDS slot c <- global (row=c>>2, k-chunk q=((c&3)-(c>>3))&3); frag reads
// slot s=(quad+(row>>1))&3 -> 2-way bank alias = free.
// EPI 0: bf16 partial store at Cp + z*Ssz, row-major ldc
// EPI 1: bf16 store C[m*ldc+n] scaled by degv[n]

#define TBK 32

template <int MT, int NT, int EPI>
__global__ __launch_bounds__(256, 3)
void gemm8(const u16* __restrict__ Ap, const u16* __restrict__ Bp,
           void* __restrict__ Cp, const float* __restrict__ degv,
           int KC, int lda, int ldb, int ldc, size_t Ssz) {
    __shared__ __align__(16) u16 Alds[MT * 32 * TBK];
    __shared__ __align__(16) u16 Blds[NT * 32 * TBK];
    const int t = threadIdx.x;
    const int m0 = blockIdx.x * (MT * 32), n0 = blockIdx.y * (NT * 32);
    const int kbase = blockIdx.z * KC;
    const int wave = t >> 6, lane = t & 63, quad = lane >> 4, lo = lane & 15;
    const int wm = (wave >> 1) * (MT * 16), wn = (wave & 1) * (NT * 16);

    f32x4 acc[MT][NT];
#pragma unroll
    for (int a = 0; a < MT; a++)
#pragma unroll
        for (int b = 0; b < NT; b++) acc[a][b] = (f32x4){0.f, 0.f, 0.f, 0.f};

    for (int kk = 0; kk < KC; kk += TBK) {
        const int k0 = kbase + kk;
        __syncthreads();
#pragma unroll
        for (int i = 0; i < MT / 2; i++) {        // A staging, swizzled gather
            int c = t + i * 256;
            int q = ((c & 3) - (c >> 3)) & 3;
            const u16* g = Ap + (size_t)(m0 + (c >> 2)) * lda + k0 + q * 8;
            __builtin_amdgcn_global_load_lds((const u32*)g, (u32*)(Alds + c * 8), 16, 0, 0);
        }
#pragma unroll
        for (int i = 0; i < NT / 2; i++) {        // B staging, swizzled gather
            int c = t + i * 256;
            int q = ((c & 3) - (c >> 3)) & 3;
            const u16* g = Bp + (size_t)(n0 + (c >> 2)) * ldb + k0 + q * 8;
            __builtin_amdgcn_global_load_lds((const u32*)g, (u32*)(Blds + c * 8), 16, 0, 0);
        }
        __syncthreads();

        bf16x8 af[MT], bfr[NT];
#pragma unroll
        for (int mt = 0; mt < MT; mt++) {
            int m = wm + mt * 16 + lo;
            int s = (quad + (m >> 1)) & 3;
            af[mt] = *(const bf16x8*)&Alds[m * TBK + s * 8];
        }
#pragma unroll
        for (int nt = 0; nt < NT; nt++) {
            int n = wn + nt * 16 + lo;
            int s = (quad + (n >> 1)) & 3;
            bfr[nt] = *(const bf16x8*)&Blds[n * TBK + s * 8];
        }
#pragma unroll
        for (int mt = 0; mt < MT; mt++)
#pragma unroll
            for (int nt = 0; nt < NT; nt++)
                acc[mt][nt] = __builtin_amdgcn_mfma_f32_16x16x32_bf16(af[mt], bfr[nt], acc[mt][nt], 0, 0, 0);
    }

    // epilogue: D[row=quad*4+i][col=lo] per 16x16 tile
    if (EPI == 0) {
        u16* C = (u16*)Cp + (size_t)blockIdx.z * Ssz;
#pragma unroll
        for (int mt = 0; mt < MT; mt++) {
            int rb = m0 + wm + mt * 16 + quad * 4;
#pragma unroll
            for (int i = 0; i < 4; i++)
#pragma unroll
                for (int nt = 0; nt < NT; nt++)
                    C[(size_t)(rb + i) * ldc + n0 + wn + nt * 16 + lo] = f2b(acc[mt][nt][i]);
        }
    } else {
        u16* C = (u16*)Cp;
        float dv[NT];
#pragma unroll
        for (int nt = 0; nt < NT; nt++) dv[nt] = degv[n0 + wn + nt * 16 + lo];
#pragma unroll
        for (int mt = 0; mt < MT; mt++) {
            int rb = m0 + wm + mt * 16 + quad * 4;
#pragma unroll
            for (int i = 0; i < 4; i++)
#pragma unroll
                for (int nt = 0; nt < NT; nt++)
                    C[(size_t)(rb + i) * ldc + n0 + wn + nt * 16 + lo] =
                        f2b(acc[mt][nt][i] * dv[nt]);
        }
    }
}

// ---------------- launch ----------------

extern "C" void kernel_launch(void* const* d_in, const int* in_sizes, int n_in,
                              void* d_out, int out_size, void* d_ws, size_t ws_size,
                              hipStream_t stream) {
    const float* x    = (const float*)d_in[0];
    const float* H    = (const float*)d_in[1];
    const float* W    = (const float*)d_in[2];
    const float* V    = (const float*)d_in[3];
    const float* bias = (const float*)d_in[4];
    float* out  = (float*)d_out;                       // (N, FT)
    float* wout = out + (size_t)N_NODES * FT;          // (E,)
    (void)in_sizes; (void)n_in; (void)out_size; (void)ws_size;

    char* wsb = (char*)d_ws;
    float* wsf   = (float*)d_ws;
    float* xv    = wsf;               // 8192 f
    float* zsum  = wsf + 8192;        // 4096 f  ┐ zeroed together (8192 f)
    float* desum = wsf + 12288;       // 4096 f  ┘
    float* degv  = wsf + 16384;       // 8192 f  (written directly, no zero)
    float* wde   = wsf + 24576;       // 4096 f -> 114,688 B
    u16*   Hbf   = (u16*)(wsb + 114688);                 // 64 MB  -> 67,223,552
    u16*   HTbf  = (u16*)(wsb + 67223552);               // 64 MB  -> 134,332,416
    u16*   WT    = (u16*)(wsb + 134332416);              // 0.5 MB -> 134,856,704
    u16*   doutT = (u16*)(wsb + 134856704);              // 8 MB   -> 143,245,312
    u16*   t2T   = (u16*)(wsb + 143245312);              // 4 MB   -> 147,439,616
    u16*   xb    = (u16*)(wsb + 147439616);              // 8 MB   -> 155,828,224
    u16*   P     = (u16*)(wsb + 155828224);              // 32 MB  -> 189,382,656

    // scalar path
    zero_kernel<<<32, 256, 0, stream>>>(zsum, 8192);     // zsum + desum
    xv_xb_kernel<<<N_NODES / 4, 256, 0, stream>>>(x, V, xv, xb);
    cvt_colsum_kernel<<<dim3(4, 256), 256, 0, stream>>>(H, xv, Hbf, zsum, desum);
    sigmoid_kernel<<<N_EDGES / 256, 256, 0, stream>>>(zsum, desum, wout, wde);
    transHb_kernel<<<dim3(N_EDGES / 64, N_NODES / 64), 256, 0, stream>>>(Hbf, HTbf);
    degv_kernel<<<N_NODES / 4, 256, 0, stream>>>(Hbf, wout, degv);
    wt_kernel<<<dim3(16, 16), dim3(32, 8), 0, stream>>>(W, WT);

    // G1: doutT[f,n] = degv[n] * sum_fi WT[f,fi]*xb[n,fi]  (M=512, N=8192, K=512) 64x128 tile
    gemm8<2, 4, 1><<<dim3(FT / 64, N_NODES / 128, 1), 256, 0, stream>>>(
        WT, xb, doutT, degv, FT, FT, FT, N_NODES, 0);

    // G2: P[z][e][f] = partial sum_n HTbf[e,n]*doutT[f,n]  (M=4096, N=512, K=8192, S=8)
    gemm8<4, 4, 0><<<dim3(N_EDGES / 128, FT / 128, 8), 256, 0, stream>>>(
        HTbf, doutT, P, nullptr, N_NODES / 8, N_NODES, N_NODES, 512, (size_t)N_EDGES * 512);

    // t2T[f,e] = wde[e] * sum_s P
    t2t_kernel<<<dim3(FT / 32, N_EDGES / 32), dim3(32, 8), 0, stream>>>(P, wde, t2T);

    // G3: P[z][n][f] = partial sum_e Hbf[n,e]*t2T[f,e]   (M=8192, N=512, K=4096, S=4)
    gemm8<4, 4, 0><<<dim3(N_NODES / 128, FT / 128, 4), 256, 0, stream>>>(
        Hbf, t2T, P, nullptr, N_EDGES / 4, N_EDGES, N_EDGES, 512, (size_t)N_NODES * 512);

    // out = degv ⊙ (sum_s P) + bias
    final_kernel<<<(N_NODES * FT / 8) / 256, 256, 0, stream>>>(P, degv, bias, out);
}

// Round 11
// 359.152 us; speedup vs baseline: 1.1811x; 1.0913x over previous
//
#include <hip/hip_runtime.h>

// HGNN conv: out = degv ⊙ (H @ ((w*deg_e) ⊙ (H^T @ (degv ⊙ (x@W))))) + bias ; w = sigmoid(H^T (x V))
// N=8192, E=4096, F=512. R11: (1) prep_h2 = fused H cvt+transpose+colsum with xv in LDS
// (broadcast, branchless) — fixes R8 prep_h's 2.4 TB/s latency bind; (2) TBK=64 GEMMs
// (half the barriers per K, rotate-by-row LDS swizzle keeps frag reads 2-way = free).

#define N_NODES 8192
#define N_EDGES 4096
#define FT 512

typedef short bf16x8 __attribute__((ext_vector_type(8)));
typedef float f32x4 __attribute__((ext_vector_type(4)));
typedef unsigned short u16;
typedef unsigned int u32;

__device__ __forceinline__ u16 f2b(float f) {
    union { float f; u32 u; } v; v.f = f;
    u32 r = v.u + 0x7FFFu + ((v.u >> 16) & 1u);   // RNE
    return (u16)(r >> 16);
}
__device__ __forceinline__ float b2f(u16 h) {
    union { u32 u; float f; } v; v.u = ((u32)h) << 16; return v.f;
}

// ---------------- scalar-path kernels ----------------

__global__ __launch_bounds__(256) void zero_kernel(float* p, int n) {
    int i = blockIdx.x * 256 + threadIdx.x;
    if (i < n) p[i] = 0.f;
}

// xv[n] = x[n,:] . V ; xb = bf16(x)
__global__ __launch_bounds__(256) void xv_xb_kernel(const float* __restrict__ x,
                                                    const float* __restrict__ V,
                                                    float* __restrict__ xv,
                                                    u16* __restrict__ xb) {
    int row = blockIdx.x * 4 + (threadIdx.x >> 6);
    int lane = threadIdx.x & 63;
    const float* xr = x + (size_t)row * FT + lane * 8;
    const float* vr = V + lane * 8;
    float4 a0 = *(const float4*)xr, a1 = *(const float4*)(xr + 4);
    float4 b0 = *(const float4*)vr, b1 = *(const float4*)(vr + 4);
    float acc = a0.x * b0.x + a0.y * b0.y + a0.z * b0.z + a0.w * b0.w +
                a1.x * b1.x + a1.y * b1.y + a1.z * b1.z + a1.w * b1.w;
    u16 tmp[8] = {f2b(a0.x), f2b(a0.y), f2b(a0.z), f2b(a0.w),
                  f2b(a1.x), f2b(a1.y), f2b(a1.z), f2b(a1.w)};
    *(uint4*)(xb + (size_t)row * FT + lane * 8) = *(uint4*)tmp;
#pragma unroll
    for (int off = 32; off; off >>= 1) acc += __shfl_down(acc, off);
    if (lane == 0) xv[row] = acc;
}

// Fused: Hbf = bf16(H); HTbf = Hbf^T; zsum[e] += sum_n H[n,e]*xv[n]; desum[e] += colsum.
// 64(e) x 64(n) tile; xv preloaded to LDS (broadcast reads), branchless cndmask accumulation.
__global__ __launch_bounds__(256) void prep_h2_kernel(const float* __restrict__ H,
                                                      const float* __restrict__ xv,
                                                      u16* __restrict__ Hbf,
                                                      u16* __restrict__ HTbf,
                                                      float* __restrict__ zsum,
                                                      float* __restrict__ desum) {
    __shared__ u32 Wt[64][33];                    // Wt[n][ew] = packed e-pair (2ew, 2ew+1)
    __shared__ float xvs[64];
    const int t = threadIdx.x;
    const int e0 = blockIdx.x * 64, n0 = blockIdx.y * 64;
    if (t < 64) xvs[t] = xv[n0 + t];
    {   // load/convert: thread (n = t>>2, seg = t&3) handles 16 e's; write Hbf
        int n = t >> 2, seg = t & 3;
        const float* src = H + (size_t)(n0 + n) * N_EDGES + e0 + seg * 16;
        u16* hdst = Hbf + (size_t)(n0 + n) * N_EDGES + e0 + seg * 16;
        u32 o[8];
#pragma unroll
        for (int j = 0; j < 4; j++) {
            float4 h = *(const float4*)(src + j * 4);
            o[2 * j]     = (h.x != 0.f ? 0x3F80u : 0u) | (h.y != 0.f ? 0x3F800000u : 0u);
            o[2 * j + 1] = (h.z != 0.f ? 0x3F80u : 0u) | (h.w != 0.f ? 0x3F800000u : 0u);
        }
        *(uint4*)hdst       = *(uint4*)&o[0];
        *(uint4*)(hdst + 8) = *(uint4*)&o[4];
#pragma unroll
        for (int j = 0; j < 8; j++) Wt[n][seg * 8 + j] = o[j];
    }
    __syncthreads();
    {   // transpose-store + colsum: thread (e = t>>2, g = t&3) handles 16 n's
        int e = t >> 2, g = t & 3;
        int ew = e >> 1;
        u32 sel = (e & 1) ? 0x07060302u : 0x05040100u;
        u32 oo[8];
        float z = 0.f, d = 0.f;
#pragma unroll
        for (int j = 0; j < 8; j++) {
            int np = g * 8 + j;
            oo[j] = __builtin_amdgcn_perm(Wt[2 * np + 1][ew], Wt[2 * np][ew], sel);
            z += (oo[j] & 0xFFFFu) ? xvs[2 * np] : 0.f;       // LDS broadcast + cndmask
            d += (oo[j] & 0xFFFFu) ? 1.f : 0.f;
            z += (oo[j] >> 16) ? xvs[2 * np + 1] : 0.f;
            d += (oo[j] >> 16) ? 1.f : 0.f;
        }
        u32* drow = (u32*)(HTbf + (size_t)(e0 + e) * N_NODES + n0);
        *(uint4*)(drow + g * 8)     = *(uint4*)&oo[0];
        *(uint4*)(drow + g * 8 + 4) = *(uint4*)&oo[4];
        z += __shfl_down(z, 2); z += __shfl_down(z, 1);
        d += __shfl_down(d, 2); d += __shfl_down(d, 1);
        if (g == 0) {
            atomicAdd(zsum + e0 + e, z);
            atomicAdd(desum + e0 + e, d);
        }
    }
}

__global__ __launch_bounds__(256) void sigmoid_kernel(const float* __restrict__ zsum,
                                                      const float* __restrict__ desum,
                                                      float* __restrict__ w_out,
                                                      float* __restrict__ wde) {
    int e = blockIdx.x * 256 + threadIdx.x;
    float z = zsum[e];
    float wv = 1.f / (1.f + expf(-z));
    w_out[e] = wv;
    wde[e] = wv * desum[e];
}

// degv[n] = Hbf[n,:] . w   (one wave per row; coalesced w loads, cndmask adds)
__global__ __launch_bounds__(256) void degv_kernel(const u16* __restrict__ Hbf,
                                                   const float* __restrict__ w,
                                                   float* __restrict__ degv) {
    int row = blockIdx.x * 4 + (threadIdx.x >> 6);
    int lane = threadIdx.x & 63;
    const uint4* hr = (const uint4*)(Hbf + (size_t)row * N_EDGES);
    float acc = 0.f;
#pragma unroll
    for (int i = 0; i < 8; i++) {
        int idx = i * 64 + lane;
        uint4 h = hr[idx];
        const float* w8 = w + idx * 8;
        float4 wa = *(const float4*)w8, wb = *(const float4*)(w8 + 4);
        acc += (h.x & 0xFFFFu) ? wa.x : 0.f;  acc += (h.x >> 16) ? wa.y : 0.f;
        acc += (h.y & 0xFFFFu) ? wa.z : 0.f;  acc += (h.y >> 16) ? wa.w : 0.f;
        acc += (h.z & 0xFFFFu) ? wb.x : 0.f;  acc += (h.z >> 16) ? wb.y : 0.f;
        acc += (h.w & 0xFFFFu) ? wb.z : 0.f;  acc += (h.w >> 16) ? wb.w : 0.f;
    }
#pragma unroll
    for (int off = 32; off; off >>= 1) acc += __shfl_down(acc, off);
    if (lane == 0) degv[row] = acc;
}

// W (FT,FT) fp32 -> WT (FT,FT) bf16 transposed
__global__ void wt_kernel(const float* __restrict__ src, u16* __restrict__ dst) {
    __shared__ float tile[32][33];
    int tx = threadIdx.x, ty = threadIdx.y;
    int c = blockIdx.x * 32 + tx;
    int r0 = blockIdx.y * 32;
#pragma unroll
    for (int i = 0; i < 4; i++)
        tile[ty + i * 8][tx] = src[(size_t)(r0 + ty + i * 8) * FT + c];
    __syncthreads();
#pragma unroll
    for (int i = 0; i < 4; i++)
        dst[(size_t)(blockIdx.x * 32 + ty + i * 8) * FT + r0 + tx] = f2b(tile[tx][ty + i * 8]);
}

// t2T[f,e] = f2b(wde[e] * sum_{s<8} P[s][e][f])
__global__ void t2t_kernel(const u16* __restrict__ P, const float* __restrict__ wde,
                           u16* __restrict__ t2T) {
    __shared__ float tile[32][33];
    int tx = threadIdx.x, ty = threadIdx.y;
    int f0 = blockIdx.x * 32, e0 = blockIdx.y * 32;
#pragma unroll
    for (int i = 0; i < 4; i++) {
        int e = e0 + ty + i * 8;
        size_t idx = (size_t)e * 512 + f0 + tx;
        float s = 0.f;
#pragma unroll
        for (int sl = 0; sl < 8; sl++)
            s += b2f(P[idx + (size_t)sl * N_EDGES * 512]);
        tile[ty + i * 8][tx] = wde[e] * s;
    }
    __syncthreads();
#pragma unroll
    for (int i = 0; i < 4; i++)
        t2T[(size_t)(f0 + ty + i * 8) * N_EDGES + e0 + tx] = f2b(tile[tx][ty + i * 8]);
}

// out[n,f] = degv[n]*sum_{s<4} P[s][n][f] + bias[f]
__global__ __launch_bounds__(256) void final_kernel(const u16* __restrict__ P,
                                                    const float* __restrict__ degv,
                                                    const float* __restrict__ bias,
                                                    float* __restrict__ out) {
    int i8 = blockIdx.x * 256 + threadIdx.x;
    int base = i8 * 8;
    int n = base >> 9, f = base & 511;
    float s[8] = {0.f, 0.f, 0.f, 0.f, 0.f, 0.f, 0.f, 0.f};
#pragma unroll
    for (int sl = 0; sl < 4; sl++) {
        uint4 v = *(const uint4*)(P + (size_t)sl * N_NODES * 512 + base);
        u32 ws[4] = {v.x, v.y, v.z, v.w};
#pragma unroll
        for (int j = 0; j < 4; j++) {
            s[2 * j]     += b2f((u16)(ws[j] & 0xFFFFu));
            s[2 * j + 1] += b2f((u16)(ws[j] >> 16));
        }
    }
    float dv = degv[n];
    float4 o0, o1;
    o0.x = dv * s[0] + bias[f + 0]; o0.y = dv * s[1] + bias[f + 1];
    o0.z = dv * s[2] + bias[f + 2]; o0.w = dv * s[3] + bias[f + 3];
    o1.x = dv * s[4] + bias[f + 4]; o1.y = dv * s[5] + bias[f + 5];
    o1.z = dv * s[6] + bias[f + 6]; o1.w = dv * s[7] + bias[f + 7];
    *(float4*)(out + base) = o0;
    *(float4*)(out + base + 4) = o1;
}

// ---------------- MFMA GEMM: TBK=64, full-DMA + rotate-by-row swizzle ----------------
// Tile (MT*32) x (NT*32), 4 waves (2x2). bf16 row-major operands, k-contiguous.
// LDS row = 64 u16 (128 B) = 8 chunks of 16 B. Chunk slot j' holds global k-chunk
// j = (j' - row) & 7 (rotate by row). Frag read for (row m, substep s2, quad):
// slot (s2*4 + quad + m) & 7 -> 16 lanes hit 8 bank-groups 2-way = free.
// 2 MFMA k-substeps per LDS tile -> half the barrier crossings of TBK=32.
// EPI 0: bf16 partial store at Cp + z*Ssz, ldc-row-major
// EPI 1: bf16 store C[m*ldc+n] scaled by degv[n]

#define TBK 64

template <int MT, int NT, int EPI>
__global__ __launch_bounds__(256, 4)
void gemm9(const u16* __restrict__ Ap, const u16* __restrict__ Bp,
           void* __restrict__ Cp, const float* __restrict__ degv,
           int KC, int lda, int ldb, int ldc, size_t Ssz) {
    __shared__ __align__(16) u16 Alds[MT * 32 * TBK];
    __shared__ __align__(16) u16 Blds[NT * 32 * TBK];
    const int t = threadIdx.x;
    const int m0 = blockIdx.x * (MT * 32), n0 = blockIdx.y * (NT * 32);
    const int kbase = blockIdx.z * KC;
    const int wave = t >> 6, lane = t & 63, quad = lane >> 4, lo = lane & 15;
    const int wm = (wave >> 1) * (MT * 16), wn = (wave & 1) * (NT * 16);

    f32x4 acc[MT][NT];
#pragma unroll
    for (int a = 0; a < MT; a++)
#pragma unroll
        for (int b = 0; b < NT; b++) acc[a][b] = (f32x4){0.f, 0.f, 0.f, 0.f};

    for (int kk = 0; kk < KC; kk += TBK) {
        const int k0 = kbase + kk;
        __syncthreads();
#pragma unroll
        for (int i = 0; i < MT; i++) {            // A: MT*32 rows x 8 chunks
            int c = t + i * 256;
            int r = c >> 3;
            int j = ((c & 7) - r) & 7;
            const u16* g = Ap + (size_t)(m0 + r) * lda + k0 + j * 8;
            __builtin_amdgcn_global_load_lds((const u32*)g, (u32*)(Alds + c * 8), 16, 0, 0);
        }
#pragma unroll
        for (int i = 0; i < NT; i++) {            // B: NT*32 rows x 8 chunks
            int c = t + i * 256;
            int r = c >> 3;
            int j = ((c & 7) - r) & 7;
            const u16* g = Bp + (size_t)(n0 + r) * ldb + k0 + j * 8;
            __builtin_amdgcn_global_load_lds((const u32*)g, (u32*)(Blds + c * 8), 16, 0, 0);
        }
        __syncthreads();

#pragma unroll
        for (int s2 = 0; s2 < 2; s2++) {
            bf16x8 af[MT], bfr[NT];
#pragma unroll
            for (int mt = 0; mt < MT; mt++) {
                int m = wm + mt * 16 + lo;
                int s = (s2 * 4 + quad + m) & 7;
                af[mt] = *(const bf16x8*)&Alds[m * TBK + s * 8];
            }
#pragma unroll
            for (int nt = 0; nt < NT; nt++) {
                int n = wn + nt * 16 + lo;
                int s = (s2 * 4 + quad + n) & 7;
                bfr[nt] = *(const bf16x8*)&Blds[n * TBK + s * 8];
            }
#pragma unroll
            for (int mt = 0; mt < MT; mt++)
#pragma unroll
                for (int nt = 0; nt < NT; nt++)
                    acc[mt][nt] = __builtin_amdgcn_mfma_f32_16x16x32_bf16(af[mt], bfr[nt], acc[mt][nt], 0, 0, 0);
        }
    }

    // epilogue: D[row=quad*4+i][col=lo] per 16x16 tile
    if (EPI == 0) {
        u16* C = (u16*)Cp + (size_t)blockIdx.z * Ssz;
#pragma unroll
        for (int mt = 0; mt < MT; mt++) {
            int rb = m0 + wm + mt * 16 + quad * 4;
#pragma unroll
            for (int i = 0; i < 4; i++)
#pragma unroll
                for (int nt = 0; nt < NT; nt++)
                    C[(size_t)(rb + i) * ldc + n0 + wn + nt * 16 + lo] = f2b(acc[mt][nt][i]);
        }
    } else {
        u16* C = (u16*)Cp;
        float dv[NT];
#pragma unroll
        for (int nt = 0; nt < NT; nt++) dv[nt] = degv[n0 + wn + nt * 16 + lo];
#pragma unroll
        for (int mt = 0; mt < MT; mt++) {
            int rb = m0 + wm + mt * 16 + quad * 4;
#pragma unroll
            for (int i = 0; i < 4; i++)
#pragma unroll
                for (int nt = 0; nt < NT; nt++)
                    C[(size_t)(rb + i) * ldc + n0 + wn + nt * 16 + lo] =
                        f2b(acc[mt][nt][i] * dv[nt]);
        }
    }
}

// ---------------- launch ----------------

extern "C" void kernel_launch(void* const* d_in, const int* in_sizes, int n_in,
                              void* d_out, int out_size, void* d_ws, size_t ws_size,
                              hipStream_t stream) {
    const float* x    = (const float*)d_in[0];
    const float* H    = (const float*)d_in[1];
    const float* W    = (const float*)d_in[2];
    const float* V    = (const float*)d_in[3];
    const float* bias = (const float*)d_in[4];
    float* out  = (float*)d_out;                       // (N, FT)
    float* wout = out + (size_t)N_NODES * FT;          // (E,)
    (void)in_sizes; (void)n_in; (void)out_size; (void)ws_size;

    char* wsb = (char*)d_ws;
    float* wsf   = (float*)d_ws;
    float* xv    = wsf;               // 8192 f
    float* zsum  = wsf + 8192;        // 4096 f  ┐ zeroed together (8192 f)
    float* desum = wsf + 12288;       // 4096 f  ┘
    float* degv  = wsf + 16384;       // 8192 f  (written directly)
    float* wde   = wsf + 24576;       // 4096 f -> 114,688 B
    u16*   Hbf   = (u16*)(wsb + 114688);                 // 64 MB  -> 67,223,552
    u16*   HTbf  = (u16*)(wsb + 67223552);               // 64 MB  -> 134,332,416
    u16*   WT    = (u16*)(wsb + 134332416);              // 0.5 MB -> 134,856,704
    u16*   doutT = (u16*)(wsb + 134856704);              // 8 MB   -> 143,245,312
    u16*   t2T   = (u16*)(wsb + 143245312);              // 4 MB   -> 147,439,616
    u16*   xb    = (u16*)(wsb + 147439616);              // 8 MB   -> 155,828,224
    u16*   P     = (u16*)(wsb + 155828224);              // 32 MB  -> 189,382,656

    // scalar path
    zero_kernel<<<32, 256, 0, stream>>>(zsum, 8192);     // zsum + desum
    xv_xb_kernel<<<N_NODES / 4, 256, 0, stream>>>(x, V, xv, xb);
    prep_h2_kernel<<<dim3(N_EDGES / 64, N_NODES / 64), 256, 0, stream>>>(
        H, xv, Hbf, HTbf, zsum, desum);
    sigmoid_kernel<<<N_EDGES / 256, 256, 0, stream>>>(zsum, desum, wout, wde);
    degv_kernel<<<N_NODES / 4, 256, 0, stream>>>(Hbf, wout, degv);
    wt_kernel<<<dim3(16, 16), dim3(32, 8), 0, stream>>>(W, WT);

    // G1: doutT[f,n] = degv[n] * sum_fi WT[f,fi]*xb[n,fi]  (M=512, N=8192, K=512) 64x128 tile
    gemm9<2, 4, 1><<<dim3(FT / 64, N_NODES / 128, 1), 256, 0, stream>>>(
        WT, xb, doutT, degv, FT, FT, FT, N_NODES, 0);

    // G2: P[z][e][f] = partial sum_n HTbf[e,n]*doutT[f,n]  (M=4096, N=512, K=8192, S=8)
    gemm9<4, 4, 0><<<dim3(N_EDGES / 128, FT / 128, 8), 256, 0, stream>>>(
        HTbf, doutT, P, nullptr, N_NODES / 8, N_NODES, N_NODES, 512, (size_t)N_EDGES * 512);

    // t2T[f,e] = wde[e] * sum_s P
    t2t_kernel<<<dim3(FT / 32, N_EDGES / 32), dim3(32, 8), 0, stream>>>(P, wde, t2T);

    // G3: P[z][n][f] = partial sum_e Hbf[n,e]*t2T[f,e]   (M=8192, N=512, K=4096, S=4)
    gemm9<4, 4, 0><<<dim3(N_NODES / 128, FT / 128, 4), 256, 0, stream>>>(
        Hbf, t2T, P, nullptr, N_EDGES / 4, N_EDGES, N_EDGES, 512, (size_t)N_NODES * 512);

    // out = degv ⊙ (sum_s P) + bias
    final_kernel<<<(N_NODES * FT / 8) / 256, 256, 0, stream>>>(P, degv, bias, out);
}